// Round 9
// baseline (49.958 us; speedup 1.0000x reference)
//
#include <hip/hip_runtime.h>

// B=128, x1/x2/x3 (B,2048,7,7) f32, W (14,2048), b (14,)
// softmax over singleton axis == 1.0 exactly  =>  h = 2*x1 + x2  (x3 unused!)
// feats[b,n] = mean_c(2*x1 + x2) ; logits = feats @ W^T + b
// Output layout: logits (128*14) then feats (128*2048), f32 flat.
//
// Round-9: zero-LDS zero-barrier streaming. Round 8 proved MLP wasn't the
// limiter (global_load_lds neutral); suspects are the load->barrier->LDS
// reduce phase structure + 4096-block ramp. One thread owns TWO rows =
// 49 float2 (8B-aligned: 392*T), row boundary at float2 #24 (elems 48|49),
// pure register reduce. 512 blocks x 256 thr. fc partials via 224-thread
// segmented dot + 16-lane shuffle tree (no atomics: round 2; no fences:
// round 7).

#define NROWS (128 * 2048)
#define FC_B 128
#define FC_N 2048
#define FC_J 14
#define NBLK 512                    // 256 threads * 2 rows = 512 rows/block
#define QPB 4                       // blocks per batch row (2048/512)

__global__ __launch_bounds__(256) void fused_kernel(
    const float* __restrict__ x1, const float* __restrict__ x2,
    const float* __restrict__ W,
    float* __restrict__ feats, float* __restrict__ part)
{
    const int tid = threadIdx.x;
    const size_t T = (size_t)blockIdx.x * 256 + tid;   // thread-pair index
    const float2* q1 = (const float2*)x1 + T * 49;     // rows 2T, 2T+1
    const float2* q2 = (const float2*)x2 + T * 49;

    // rows A = 2T (elements 0..48), B = 2T+1 (elements 49..97)
    float s1A = 0.f, s1B = 0.f, s2A = 0.f, s2B = 0.f;

    #pragma unroll
    for (int m = 0; m < 24; ++m) {          // both elems in row A
        const float2 a = q1[m];
        const float2 c = q2[m];
        s1A += a.x + a.y;
        s2A += c.x + c.y;
    }
    {                                        // m = 24: elems 48 | 49 split
        const float2 a = q1[24];
        const float2 c = q2[24];
        s1A += a.x;  s1B += a.y;
        s2A += c.x;  s2B += c.y;
    }
    #pragma unroll
    for (int m = 25; m < 49; ++m) {         // both elems in row B
        const float2 a = q1[m];
        const float2 c = q2[m];
        s1B += a.x + a.y;
        s2B += c.x + c.y;
    }

    float2 fv;
    fv.x = (2.0f * s1A + s2A) * (1.0f / 49.0f);
    fv.y = (2.0f * s1B + s2B) * (1.0f / 49.0f);
    ((float2*)feats)[T] = fv;                // coalesced 8B/lane write

    // ---- fc partials: block owns 512 consecutive n of batch bb ----
    __shared__ float sf[512];
    ((float2*)sf)[tid] = fv;
    __syncthreads();

    if (tid < 224) {
        const int j = tid >> 4;              // 0..13
        const int s = tid & 15;              // segment lane
        const int bb = blockIdx.x >> 2;      // batch index
        const int q  = blockIdx.x & (QPB - 1);
        const float* wrow = W + j * FC_N + q * 512;   // W is L2-resident
        float acc = 0.0f;
        #pragma unroll
        for (int k = 0; k < 32; ++k)
            acc += sf[s + 16 * k] * wrow[s + 16 * k];
        acc += __shfl_xor(acc, 1, 16);
        acc += __shfl_xor(acc, 2, 16);
        acc += __shfl_xor(acc, 4, 16);
        acc += __shfl_xor(acc, 8, 16);
        if (s == 0)
            part[((bb * FC_J + j) << 2) + q] = acc;   // part[b][j][q]
    }
}

__global__ __launch_bounds__(256) void gather_kernel(const float* __restrict__ part,
                                                     const float* __restrict__ bias,
                                                     float* __restrict__ logits) {
    const int idx = blockIdx.x * 256 + threadIdx.x;
    if (idx >= FC_B * FC_J) return;
    const float4 p = *(const float4*)(part + ((size_t)idx << 2));
    logits[idx] = p.x + p.y + p.z + p.w + bias[idx % FC_J];
}

extern "C" void kernel_launch(void* const* d_in, const int* in_sizes, int n_in,
                              void* d_out, int out_size, void* d_ws, size_t ws_size,
                              hipStream_t stream) {
    const float* x1 = (const float*)d_in[0];
    const float* x2 = (const float*)d_in[1];
    // d_in[2] = x3 — provably unused (softmax over singleton axis == 1)
    const float* W = (const float*)d_in[3];
    const float* bias = (const float*)d_in[4];

    float* out = (float*)d_out;
    float* logits = out;                 // 128*14
    float* feats = out + FC_B * FC_J;    // 128*2048

    float* part = (float*)d_ws;          // 128*14*4*4 = 28 KB scratch

    fused_kernel<<<NBLK, 256, 0, stream>>>(x1, x2, W, feats, part);
    gather_kernel<<<(FC_B * FC_J + 255) / 256, 256, 0, stream>>>(part, bias, logits);
}

// Round 10
// 22.564 us; speedup vs baseline: 2.2141x; 2.2141x over previous
//
#include <hip/hip_runtime.h>

// B=128, x1/x2/x3 (B,2048,7,7) f32, W (14,2048), b (14,)
// softmax over singleton axis == 1.0 exactly  =>  h = 2*x1 + x2  (x3 unused!)
// feats[b,n] = mean_c(2*x1 + x2) ; logits = feats @ W^T + b
// Output layout: logits (128*14) then feats (128*2048), f32 flat.
//
// Round-10: 2-phase pipelined streaming (guide T3 minimum template).
// Round 9 proved per-lane strided streaming is a disaster (130MB fetch,
// 2.2TB/s) -> block-tile float4 coalescing (round 5) is the right load
// shape. Round 5's residue: __syncthreads drains vmcnt(0) every tile, so
// reduce phases issue no memory traffic. Here: 1024 persistent blocks
// (4/CU, all resident), 4 tiles of 64 rows each, double-buffered LDS,
// reg-staged prefetch of tile t+1 issued BEFORE a raw s_barrier with only
// lgkmcnt(0) drained -- loads stay in flight across the barrier.
// No atomics (r2), no fences (r7), no coop launch (r6).

#define FC_B 128
#define FC_N 2048
#define FC_J 14
#define TILE_ROWS 64
#define TILE_F (TILE_ROWS * 49)         // 3136 floats
#define TILE_V (TILE_F / 4)             // 784 float4
#define TPB 4                           // tiles per block
#define RPB (TPB * TILE_ROWS)           // 256 rows per block
#define NBLK (FC_B * FC_N / RPB)        // 1024 blocks = 4/CU
#define BPB (FC_N / RPB)                // 8 blocks per batch row

__global__ __launch_bounds__(256) void fused_kernel(
    const float* __restrict__ x1, const float* __restrict__ x2,
    const float* __restrict__ W,
    float* __restrict__ feats, float* __restrict__ part)
{
    const int tid = threadIdx.x;
    __shared__ float buf[2][TILE_F];                 // 25088 B
    __shared__ __align__(16) float sf[RPB];          // 1024 B

    const float4* q1 = (const float4*)x1 + (size_t)blockIdx.x * (TPB * TILE_V);
    const float4* q2 = (const float4*)x2 + (size_t)blockIdx.x * (TPB * TILE_V);

    float4 r1a, r1b, r1c, r2a, r2b, r2c, tl1, tl2;

    // prologue: load tile 0 into registers
    r1a = q1[tid]; r1b = q1[tid + 256]; r1c = q1[tid + 512];
    r2a = q2[tid]; r2b = q2[tid + 256]; r2c = q2[tid + 512];
    if (tid < 16) { tl1 = q1[768 + tid]; tl2 = q2[768 + tid]; }

    const int row = tid >> 2;            // 0..63
    const int tt = tid & 3;

    #pragma unroll
    for (int t = 0; t < TPB; ++t) {
        // ---- combine 2*x1+x2 in registers, write to LDS buf[t&1] ----
        float4* smv = (float4*)buf[t & 1];
        float4 w0, w1, w2;
        w0.x = 2.f*r1a.x + r2a.x; w0.y = 2.f*r1a.y + r2a.y;
        w0.z = 2.f*r1a.z + r2a.z; w0.w = 2.f*r1a.w + r2a.w;
        w1.x = 2.f*r1b.x + r2b.x; w1.y = 2.f*r1b.y + r2b.y;
        w1.z = 2.f*r1b.z + r2b.z; w1.w = 2.f*r1b.w + r2b.w;
        w2.x = 2.f*r1c.x + r2c.x; w2.y = 2.f*r1c.y + r2c.y;
        w2.z = 2.f*r1c.z + r2c.z; w2.w = 2.f*r1c.w + r2c.w;
        smv[tid] = w0; smv[tid + 256] = w1; smv[tid + 512] = w2;
        if (tid < 16) {
            float4 wt;
            wt.x = 2.f*tl1.x + tl2.x; wt.y = 2.f*tl1.y + tl2.y;
            wt.z = 2.f*tl1.z + tl2.z; wt.w = 2.f*tl1.w + tl2.w;
            smv[768 + tid] = wt;
        }

        // ---- issue prefetch of tile t+1 BEFORE the barrier (stays in
        // flight: raw s_barrier drains lgkm only, not vmcnt) ----
        if (t < TPB - 1) {
            const float4* Q1 = q1 + (t + 1) * TILE_V;
            const float4* Q2 = q2 + (t + 1) * TILE_V;
            r1a = Q1[tid]; r1b = Q1[tid + 256]; r1c = Q1[tid + 512];
            r2a = Q2[tid]; r2b = Q2[tid + 256]; r2c = Q2[tid + 512];
            if (tid < 16) { tl1 = Q1[768 + tid]; tl2 = Q2[768 + tid]; }
        }

        asm volatile("s_waitcnt lgkmcnt(0)" ::: "memory");
        __builtin_amdgcn_s_barrier();

        // ---- row reduce from buf[t&1]: 4 threads/row ----
        const float* rp = buf[t & 1] + row * 49;
        float v = 0.f;
        #pragma unroll
        for (int k = 0; k < 12; ++k)
            v += rp[tt + 4 * k];
        if (tt == 0) v += rp[48];
        v += __shfl_xor(v, 1, 4);
        v += __shfl_xor(v, 2, 4);
        if (tt == 0) sf[t * TILE_ROWS + row] = v * (1.0f / 49.0f);
        // next iteration's lgkmcnt(0)+barrier protects buf reuse (WAR) and
        // orders sf writes; double buffer makes 1 barrier/iter sufficient.
    }

    asm volatile("s_waitcnt lgkmcnt(0)" ::: "memory");
    __builtin_amdgcn_s_barrier();

    // ---- coalesced feats write: 64 lanes x float4 = 256 rows ----
    if (tid < 64)
        ((float4*)(feats + (size_t)blockIdx.x * RPB))[tid] =
            ((const float4*)sf)[tid];

    // ---- fc partials: 224 threads, 16-lane segmented dot ----
    if (tid < 224) {
        const int j = tid >> 4;              // 0..13
        const int s = tid & 15;
        const int bb = blockIdx.x >> 3;      // batch index (8 blocks/batch)
        const int blkin = blockIdx.x & (BPB - 1);
        const float* wrow = W + j * FC_N + blkin * RPB;   // W is L2-resident
        float acc = 0.f;
        #pragma unroll
        for (int k = 0; k < 16; ++k)
            acc += sf[s + 16 * k] * wrow[s + 16 * k];
        acc += __shfl_xor(acc, 1, 16);
        acc += __shfl_xor(acc, 2, 16);
        acc += __shfl_xor(acc, 4, 16);
        acc += __shfl_xor(acc, 8, 16);
        if (s == 0)
            part[((bb * FC_J + j) << 3) + blkin] = acc;   // part[b][j][blkin]
    }
}

__global__ __launch_bounds__(256) void gather_kernel(const float* __restrict__ part,
                                                     const float* __restrict__ bias,
                                                     float* __restrict__ logits) {
    const int idx = blockIdx.x * 256 + threadIdx.x;
    if (idx >= FC_B * FC_J) return;
    const float4 p0 = ((const float4*)(part + ((size_t)idx << 3)))[0];
    const float4 p1 = ((const float4*)(part + ((size_t)idx << 3)))[1];
    logits[idx] = p0.x + p0.y + p0.z + p0.w
                + p1.x + p1.y + p1.z + p1.w + bias[idx % FC_J];
}

extern "C" void kernel_launch(void* const* d_in, const int* in_sizes, int n_in,
                              void* d_out, int out_size, void* d_ws, size_t ws_size,
                              hipStream_t stream) {
    const float* x1 = (const float*)d_in[0];
    const float* x2 = (const float*)d_in[1];
    // d_in[2] = x3 — provably unused (softmax over singleton axis == 1)
    const float* W = (const float*)d_in[3];
    const float* bias = (const float*)d_in[4];

    float* out = (float*)d_out;
    float* logits = out;                 // 128*14
    float* feats = out + FC_B * FC_J;    // 128*2048

    float* part = (float*)d_ws;          // 128*14*8*4 = 57 KB scratch

    fused_kernel<<<NBLK, 256, 0, stream>>>(x1, x2, W, feats, part);
    gather_kernel<<<(FC_B * FC_J + 255) / 256, 256, 0, stream>>>(part, bias, logits);
}